// Round 2
// baseline (592.490 us; speedup 1.0000x reference)
//
#include <hip/hip_runtime.h>
#include <math.h>

// Problem constants
#define BB 16
#define HH 64
#define LL 16384
#define NST 32
#define LC 256
#define CC 64              // LL/LC
#define BL (BB*LL)         // 262144

// ws layout (float offsets). Total ~84 MB.
#define OFF_H   ((size_t)0)                       // h / y1 buffer: 16,777,216 floats
#define OFF_P   ((size_t)16777216)                // chunk states: float2 x 2,097,152
#define OFF_PW  (OFF_P + (size_t)4194304)         // per-state params float4 x 2048
#define OFF_WL  (OFF_PW + (size_t)8192)           // w^Lc: float2 x 2048
#define OFF_GB  (OFF_WL + (size_t)4096)           // FiLM gamma/beta: 2048
#define OFF_BN  (OFF_GB + (size_t)2048)           // BN sum/sumsq: 128
#define OFF_BNF (OFF_BN + (size_t)128)            // BN mean/inv: 128

// ---------------------------------------------------------------------------
// K0: derived S4D params (w, 2*Cd, w^Lc), FiLM gamma/beta, zero BN sums.
// ---------------------------------------------------------------------------
__global__ void k0_setup(const float* __restrict__ log_dt,
                         const float* __restrict__ log_A_real,
                         const float* __restrict__ A_imag,
                         const float* __restrict__ C_re,
                         const float* __restrict__ C_im,
                         const float* __restrict__ cond,
                         const float* __restrict__ film_w,
                         const float* __restrict__ film_b,
                         float* __restrict__ ws) {
    int t = threadIdx.x;
    if (blockIdx.x == 0) {
        float4* pw = (float4*)(ws + OFF_PW);
        float2* wl = (float2*)(ws + OFF_WL);
        for (int k = 0; k < 8; k++) {
            int idx = k * 256 + t;           // state index = ch*32 + n
            int ch = idx >> 5;
            float dt  = expf(log_dt[ch]);
            float are = -expf(log_A_real[idx]);
            float aim = A_imag[idx];
            float dr = are * dt, di = aim * dt;
            float er = expf(dr);
            float wr = er * cosf(di);
            float wi = er * sinf(di);
            // Cd = (C_re + i C_im) * (w - 1) / A ;  A = are + i aim
            float inv = 1.0f / (are * are + aim * aim);
            float gr = ((wr - 1.0f) * are + wi * aim) * inv;
            float gi = (wi * are - (wr - 1.0f) * aim) * inv;
            float cr = C_re[idx], ci = C_im[idx];
            float cdr = cr * gr - ci * gi;
            float cdi = cr * gi + ci * gr;
            pw[idx] = make_float4(wr, wi, 2.0f * cdr, 2.0f * cdi);
            float erL = expf(dr * (float)LC);
            wl[idx] = make_float2(erL * cosf(di * (float)LC), erL * sinf(di * (float)LC));
        }
    } else if (blockIdx.x == 1) {
        float* gb = ws + OFF_GB;
        for (int k = 0; k < 8; k++) {
            int o = k * 256 + t;             // o = b*128 + j
            int b = o >> 7, j = o & 127;
            float acc = film_b[j];
            for (int q = 0; q < 128; q++)
                acc = fmaf(cond[b * 128 + q], film_w[j * 128 + q], acc);
            gb[o] = acc;
        }
    } else {
        if (t < 128) ws[OFF_BN + t] = 0.0f;
    }
}

// ---------------------------------------------------------------------------
// Channel-mix GEMM: dst[b,g,l] = (opt prelu)( sum_h W[g,h]*src[b,h,l] + bias[g] )
// One thread per l; x column (64) in VGPRs; W read with wave-uniform indices
// (scalar-load path — no LDS broadcast traffic).
// ---------------------------------------------------------------------------
__global__ __launch_bounds__(256) void k_chanmix(const float* __restrict__ src,
                                                 const float* __restrict__ W,
                                                 const float* __restrict__ bias,
                                                 float* __restrict__ dst,
                                                 const float* __restrict__ aptr,
                                                 int do_prelu) {
    int t = threadIdx.x;
    int bi = blockIdx.x;
    int b = bi >> 6;
    int l = ((bi & 63) << 8) + t;
    float a1 = *aptr;
    const float* sp = src + (size_t)b * HH * LL + l;
    float xv[64];
#pragma unroll
    for (int ch = 0; ch < 64; ch++) xv[ch] = sp[(size_t)ch * LL];
    float* dp = dst + (size_t)b * HH * LL + l;
    const float4* W4 = (const float4*)W;
    for (int g = 0; g < 64; g++) {
        float acc0 = bias[g];      // uniform -> s_load
        float acc1 = 0.0f;
#pragma unroll
        for (int hh = 0; hh < 8; hh++) {
            float4 wa = W4[g * 16 + hh];          // uniform -> s_load_dwordx4
            float4 wb = W4[g * 16 + 8 + hh];
            acc0 = fmaf(wa.x, xv[hh * 4 + 0], acc0);
            acc0 = fmaf(wa.y, xv[hh * 4 + 1], acc0);
            acc0 = fmaf(wa.z, xv[hh * 4 + 2], acc0);
            acc0 = fmaf(wa.w, xv[hh * 4 + 3], acc0);
            acc1 = fmaf(wb.x, xv[32 + hh * 4 + 0], acc1);
            acc1 = fmaf(wb.y, xv[32 + hh * 4 + 1], acc1);
            acc1 = fmaf(wb.z, xv[32 + hh * 4 + 2], acc1);
            acc1 = fmaf(wb.w, xv[32 + hh * 4 + 3], acc1);
        }
        float acc = acc0 + acc1;
        if (do_prelu) acc = (acc >= 0.0f) ? acc : a1 * acc;
        dp[(size_t)g * LL] = acc;
    }
}

// ---------------------------------------------------------------------------
// K2 phase A: per (b, chunk, ch) compute local chunk-end partial states.
// 128 threads = 32 channels x 4 lanes; 8 complex states per lane.
// Chunk processed in two 128-col halves (LDS 16.9 KB -> 9 blocks/CU).
// ---------------------------------------------------------------------------
__global__ __launch_bounds__(128) void k2_phaseA(float* __restrict__ ws) {
    __shared__ __align__(16) float hl[32 * 132];
    int t = threadIdx.x;
    int bi = blockIdx.x;          // b * 128 + c*2 + half
    int b = bi >> 7;
    int rem = bi & 127;
    int c = rem >> 1;
    int half = rem & 1;
    const float* hbase = ws + OFF_H + ((size_t)b * HH + half * 32) * LL + (size_t)c * LC;
    int chl = t >> 2;
    int sub = t & 3;
    int ch = half * 32 + chl;
    const float4* pw = (const float4*)(ws + OFF_PW);
    float wr[8], wi[8], pr[8], pi[8];
#pragma unroll
    for (int k = 0; k < 8; k++) {
        float4 p = pw[ch * 32 + sub * 8 + k];
        wr[k] = p.x; wi[k] = p.y; pr[k] = 0.0f; pi[k] = 0.0f;
    }
    const float* hrow = &hl[chl * 132];
    for (int hh = 0; hh < 2; hh++) {
        __syncthreads();
        for (int i = 0; i < 8; i++) {
            int idx = i * 128 + t;        // 1024 float4 per half
            int r = idx >> 5;
            int f = idx & 31;
            *(float4*)&hl[r * 132 + f * 4] =
                *(const float4*)(hbase + (size_t)r * LL + hh * 128 + f * 4);
        }
        __syncthreads();
        for (int j0 = 0; j0 < 128; j0 += 4) {
            float4 hq = *(const float4*)&hrow[j0];
#pragma unroll
            for (int u = 0; u < 4; u++) {
                float hv = (u == 0) ? hq.x : (u == 1) ? hq.y : (u == 2) ? hq.z : hq.w;
#pragma unroll
                for (int k = 0; k < 8; k++) {
                    float nr = fmaf(wr[k], pr[k], fmaf(-wi[k], pi[k], hv));
                    float ni = fmaf(wi[k], pr[k], wr[k] * pi[k]);
                    pr[k] = nr; pi[k] = ni;
                }
            }
        }
    }
    float2* P = (float2*)(ws + OFF_P);
    size_t base = ((size_t)b * CC + c) * 2048 + ch * 32 + sub * 8;
#pragma unroll
    for (int k = 0; k < 8; k++) P[base + k] = make_float2(pr[k], pi[k]);
}

// ---------------------------------------------------------------------------
// K3: sequential carry scan over chunks (in-place: P[c] becomes S_in[c]).
// ---------------------------------------------------------------------------
__global__ __launch_bounds__(256) void k3_scan(float* __restrict__ ws) {
    int tid = blockIdx.x * 256 + threadIdx.x;  // 0..32767
    int b = tid >> 11;
    int r = tid & 2047;
    float2* P = (float2*)(ws + OFF_P);
    float2 wl = ((const float2*)(ws + OFF_WL))[r];
    float sr = 0.0f, si = 0.0f;
    for (int c = 0; c < CC; c++) {
        size_t idx = ((size_t)b * CC + c) * 2048 + r;
        float2 pc = P[idx];
        P[idx] = make_float2(sr, si);
        float nr = fmaf(wl.x, sr, fmaf(-wl.y, si, pc.x));
        float ni = fmaf(wl.y, sr, fmaf(wl.x, si, pc.y));
        sr = nr; si = ni;
    }
}

// ---------------------------------------------------------------------------
// K4 phase C: full recurrence with carry-in; y1 = conv + Dskip*h, in-place.
// Same two-half LDS structure as k2.
// ---------------------------------------------------------------------------
__global__ __launch_bounds__(128) void k4_phaseC(float* __restrict__ ws,
                                                 const float* __restrict__ Dskip) {
    __shared__ __align__(16) float hl[32 * 132];
    int t = threadIdx.x;
    int bi = blockIdx.x;
    int b = bi >> 7;
    int rem = bi & 127;
    int c = rem >> 1;
    int half = rem & 1;
    float* hbase = ws + OFF_H + ((size_t)b * HH + half * 32) * LL + (size_t)c * LC;
    int chl = t >> 2;
    int sub = t & 3;
    int ch = half * 32 + chl;
    const float4* pw = (const float4*)(ws + OFF_PW);
    const float2* P = (const float2*)(ws + OFF_P);
    size_t pbase = ((size_t)b * CC + c) * 2048 + ch * 32 + sub * 8;
    float wr[8], wi[8], cr[8], ci[8], sr[8], si[8];
#pragma unroll
    for (int k = 0; k < 8; k++) {
        float4 p = pw[ch * 32 + sub * 8 + k];
        wr[k] = p.x; wi[k] = p.y; cr[k] = p.z; ci[k] = p.w;
        float2 s0 = P[pbase + k];
        sr[k] = s0.x; si[k] = s0.y;
    }
    float dsk = Dskip[ch];
    float* hrow = &hl[chl * 132];
    for (int hh = 0; hh < 2; hh++) {
        __syncthreads();
        for (int i = 0; i < 8; i++) {
            int idx = i * 128 + t;
            int r = idx >> 5;
            int f = idx & 31;
            *(float4*)&hl[r * 132 + f * 4] =
                *(const float4*)(hbase + (size_t)r * LL + hh * 128 + f * 4);
        }
        __syncthreads();
        for (int j0 = 0; j0 < 128; j0 += 4) {
            float4 hq = *(const float4*)&hrow[j0];
            float4 ov;
#pragma unroll
            for (int u = 0; u < 4; u++) {
                float hv = (u == 0) ? hq.x : (u == 1) ? hq.y : (u == 2) ? hq.z : hq.w;
                float a0 = 0.0f, a1 = 0.0f;
#pragma unroll
                for (int k = 0; k < 8; k++) {
                    float nr = fmaf(wr[k], sr[k], fmaf(-wi[k], si[k], hv));
                    float ni = fmaf(wi[k], sr[k], wr[k] * si[k]);
                    sr[k] = nr; si[k] = ni;
                    if (k < 4) {
                        a0 = fmaf(cr[k], nr, a0);
                        a0 = fmaf(-ci[k], ni, a0);
                    } else {
                        a1 = fmaf(cr[k], nr, a1);
                        a1 = fmaf(-ci[k], ni, a1);
                    }
                }
                float acc = a0 + a1;
                acc += __shfl_xor(acc, 1);
                acc += __shfl_xor(acc, 2);
                float res = fmaf(dsk, hv, acc);
                if (u == 0) ov.x = res; else if (u == 1) ov.y = res;
                else if (u == 2) ov.z = res; else ov.w = res;
            }
            if (sub == 0) *(float4*)&hrow[j0] = ov;
        }
        __syncthreads();
        for (int i = 0; i < 8; i++) {
            int idx = i * 128 + t;
            int r = idx >> 5;
            int f = idx & 31;
            *(float4*)(hbase + (size_t)r * LL + hh * 128 + f * 4) =
                *(const float4*)&hl[r * 132 + f * 4];
        }
    }
}

// ---------------------------------------------------------------------------
// K5b: BN partial sums per channel (one block per (b,ch) row).
// ---------------------------------------------------------------------------
__global__ __launch_bounds__(256) void k5b_bnsum(const float* __restrict__ y2,
                                                 float* __restrict__ ws) {
    int bi = blockIdx.x;      // row = b*64+ch
    int t = threadIdx.x;
    const float4* r4 = (const float4*)(y2 + (size_t)bi * LL);
    float s = 0.0f, ss = 0.0f;
    for (int i = 0; i < 16; i++) {
        float4 v = r4[t + i * 256];
        s += v.x + v.y + v.z + v.w;
        ss += v.x * v.x + v.y * v.y + v.z * v.z + v.w * v.w;
    }
    for (int off = 32; off; off >>= 1) {
        s += __shfl_xor(s, off);
        ss += __shfl_xor(ss, off);
    }
    __shared__ float wsum[4], wsq[4];
    int wv = t >> 6;
    if ((t & 63) == 0) { wsum[wv] = s; wsq[wv] = ss; }
    __syncthreads();
    if (t == 0) {
        float S = wsum[0] + wsum[1] + wsum[2] + wsum[3];
        float SS = wsq[0] + wsq[1] + wsq[2] + wsq[3];
        int ch = bi & 63;
        atomicAdd(ws + OFF_BN + ch, S);
        atomicAdd(ws + OFF_BN + 64 + ch, SS);
    }
}

__global__ void k5c_bnfin(float* __restrict__ ws) {
    int t = threadIdx.x;      // 64 threads
    float cnt = (float)BL;
    float mean = ws[OFF_BN + t] / cnt;
    float var = ws[OFF_BN + 64 + t] / cnt - mean * mean;
    ws[OFF_BNF + t] = mean;
    ws[OFF_BNF + 64 + t] = 1.0f / sqrtf(var + 1e-5f);
}

// ---------------------------------------------------------------------------
// K6: BN apply + FiLM + PReLU + depthwise residual, in-place over d_out.
// ---------------------------------------------------------------------------
__global__ __launch_bounds__(256) void k6_final(const float* __restrict__ x,
                                                const float* __restrict__ ws,
                                                const float* __restrict__ a2p,
                                                const float* __restrict__ res_w,
                                                float* __restrict__ out) {
    int bi = blockIdx.x;      // 16 blocks per row
    int t = threadIdx.x;
    int row = bi >> 4;
    int b = row >> 6, ch = row & 63;
    float gamma = ws[OFF_GB + b * 128 + ch];
    float beta  = ws[OFF_GB + b * 128 + 64 + ch];
    float mean = ws[OFF_BNF + ch];
    float inv  = ws[OFF_BNF + 64 + ch];
    float scale = gamma * inv;
    float shift = beta - scale * mean;
    float rw = res_w[ch];
    float a2 = *a2p;
    size_t i4 = (size_t)row * (LL / 4) + (size_t)(bi & 15) * 256 + t;
    float4 y = ((const float4*)out)[i4];
    float4 xv = ((const float4*)x)[i4];
    float v;
    v = fmaf(scale, y.x, shift); v = (v >= 0.0f) ? v : a2 * v; y.x = fmaf(rw, xv.x, v);
    v = fmaf(scale, y.y, shift); v = (v >= 0.0f) ? v : a2 * v; y.y = fmaf(rw, xv.y, v);
    v = fmaf(scale, y.z, shift); v = (v >= 0.0f) ? v : a2 * v; y.z = fmaf(rw, xv.z, v);
    v = fmaf(scale, y.w, shift); v = (v >= 0.0f) ? v : a2 * v; y.w = fmaf(rw, xv.w, v);
    ((float4*)out)[i4] = y;
}

// ---------------------------------------------------------------------------
extern "C" void kernel_launch(void* const* d_in, const int* in_sizes, int n_in,
                              void* d_out, int out_size, void* d_ws, size_t ws_size,
                              hipStream_t stream) {
    const float* x        = (const float*)d_in[0];
    const float* cond     = (const float*)d_in[1];
    const float* linear_w = (const float*)d_in[2];
    const float* linear_b = (const float*)d_in[3];
    const float* prelu1_a = (const float*)d_in[4];
    const float* log_dt   = (const float*)d_in[5];
    const float* log_A    = (const float*)d_in[6];
    const float* A_imag   = (const float*)d_in[7];
    const float* C_re     = (const float*)d_in[8];
    const float* C_im     = (const float*)d_in[9];
    const float* Dskip    = (const float*)d_in[10];
    const float* out_w    = (const float*)d_in[11];
    const float* out_b    = (const float*)d_in[12];
    const float* film_w   = (const float*)d_in[13];
    const float* film_b   = (const float*)d_in[14];
    const float* prelu2_a = (const float*)d_in[15];
    const float* res_w    = (const float*)d_in[16];
    float* ws  = (float*)d_ws;
    float* out = (float*)d_out;

    hipLaunchKernelGGL(k0_setup, dim3(3), dim3(256), 0, stream,
                       log_dt, log_A, A_imag, C_re, C_im, cond, film_w, film_b, ws);
    hipLaunchKernelGGL(k_chanmix, dim3(1024), dim3(256), 0, stream,
                       x, linear_w, linear_b, ws + OFF_H, prelu1_a, 1);
    hipLaunchKernelGGL(k2_phaseA, dim3(2048), dim3(128), 0, stream, ws);
    hipLaunchKernelGGL(k3_scan, dim3(128), dim3(256), 0, stream, ws);
    hipLaunchKernelGGL(k4_phaseC, dim3(2048), dim3(128), 0, stream, ws, Dskip);
    hipLaunchKernelGGL(k_chanmix, dim3(1024), dim3(256), 0, stream,
                       ws + OFF_H, out_w, out_b, out, prelu1_a, 0);
    hipLaunchKernelGGL(k5b_bnsum, dim3(1024), dim3(256), 0, stream, out, ws);
    hipLaunchKernelGGL(k5c_bnfin, dim3(1), dim3(64), 0, stream, ws);
    hipLaunchKernelGGL(k6_final, dim3(16384), dim3(256), 0, stream,
                       x, ws, prelu2_a, res_w, out);
}

// Round 4
// 424.023 us; speedup vs baseline: 1.3973x; 1.3973x over previous
//
#include <hip/hip_runtime.h>
#include <math.h>

// Problem constants
#define BB 16
#define HH 64
#define LL 16384
#define NST 32
#define LC 256
#define CC 64              // LL/LC
#define BL (BB*LL)         // 262144

typedef _Float16 f16;
typedef f16  f16x8 __attribute__((ext_vector_type(8)));
typedef float f32x4 __attribute__((ext_vector_type(4)));

// ws layout (float offsets). Total ~71.4 MB.
// NOTE: y1 is written IN PLACE over OFF_H by gemmMain (each (ch,col) owned by
// exactly one block; gemmA, the only other H reader, runs before it).
#define OFF_H   ((size_t)0)            // h f16 -> later y1 f16: 16,777,216 halves
#define OFF_P   ((size_t)8388608)      // P fp32: 64ch x 64row x 1024col
#define OFF_S   ((size_t)12582912)     // S_t f16: [ch][1024 col][64 row]
#define OFF_T   ((size_t)14680064)     // T f16: [ch][256][256]
#define OFF_V   ((size_t)16777216)     // V f16: [ch][64][256]
#define OFF_U   ((size_t)17301504)     // U f16: [ch][256][64]
#define OFF_PW  ((size_t)17825792)     // per-state params float4 x 2048
#define OFF_WL  ((size_t)17833984)     // w^Lc: float2 x 2048
#define OFF_GB  ((size_t)17838080)     // FiLM gamma/beta: 2048
#define OFF_BN  ((size_t)17840128)     // BN sum/sumsq: 128
#define OFF_BNF ((size_t)17840256)     // BN mean/inv: 128

// ---------------------------------------------------------------------------
// K0: derived S4D params (w, 2*Cd, w^Lc), FiLM gamma/beta, zero BN sums.
// ---------------------------------------------------------------------------
__global__ void k0_setup(const float* __restrict__ log_dt,
                         const float* __restrict__ log_A_real,
                         const float* __restrict__ A_imag,
                         const float* __restrict__ C_re,
                         const float* __restrict__ C_im,
                         const float* __restrict__ cond,
                         const float* __restrict__ film_w,
                         const float* __restrict__ film_b,
                         float* __restrict__ ws) {
    int t = threadIdx.x;
    if (blockIdx.x == 0) {
        float4* pw = (float4*)(ws + OFF_PW);
        float2* wl = (float2*)(ws + OFF_WL);
        for (int k = 0; k < 8; k++) {
            int idx = k * 256 + t;           // state index = ch*32 + n
            int ch = idx >> 5;
            float dt  = expf(log_dt[ch]);
            float are = -expf(log_A_real[idx]);
            float aim = A_imag[idx];
            float dr = are * dt, di = aim * dt;
            float er = expf(dr);
            float wr = er * cosf(di);
            float wi = er * sinf(di);
            float inv = 1.0f / (are * are + aim * aim);
            float gr = ((wr - 1.0f) * are + wi * aim) * inv;
            float gi = (wi * are - (wr - 1.0f) * aim) * inv;
            float cr = C_re[idx], ci = C_im[idx];
            float cdr = cr * gr - ci * gi;
            float cdi = cr * gi + ci * gr;
            pw[idx] = make_float4(wr, wi, 2.0f * cdr, 2.0f * cdi);
            float erL = expf(dr * (float)LC);
            wl[idx] = make_float2(erL * cosf(di * (float)LC), erL * sinf(di * (float)LC));
        }
    } else if (blockIdx.x == 1) {
        float* gb = ws + OFF_GB;
        for (int k = 0; k < 8; k++) {
            int o = k * 256 + t;             // o = b*128 + j
            int b = o >> 7, j = o & 127;
            float acc = film_b[j];
            for (int q = 0; q < 128; q++)
                acc = fmaf(cond[b * 128 + q], film_w[j * 128 + q], acc);
            gb[o] = acc;
        }
    } else {
        if (t < 128) ws[OFF_BN + t] = 0.0f;
    }
}

// ---------------------------------------------------------------------------
// KBUILD: per-channel f16 matrices: T (Toeplitz K'[i-j], Dskip on diag),
// V (Vandermonde w^{255-j} re/im rows), U (2Cd*w^{l+1} carry matrix).
// One block per channel.
// ---------------------------------------------------------------------------
__global__ __launch_bounds__(256) void kbuild(const float* __restrict__ log_dt,
                                              const float* __restrict__ log_A,
                                              const float* __restrict__ A_imag,
                                              const float* __restrict__ Dskip,
                                              float* __restrict__ ws) {
    __shared__ float Kl[256];
    __shared__ float drs[32], dis[32], c2r[32], c2i[32];
    int ch = blockIdx.x, t = threadIdx.x;
    if (t < 32) {
        float dt = expf(log_dt[ch]);
        float are = -expf(log_A[ch * 32 + t]);
        float aim = A_imag[ch * 32 + t];
        drs[t] = are * dt; dis[t] = aim * dt;
        float4 p = ((const float4*)(ws + OFF_PW))[ch * 32 + t];
        c2r[t] = p.z; c2i[t] = p.w;
    }
    __syncthreads();
    // K'[d], d = t
    float acc = 0.0f;
    float fd = (float)t;
    for (int n = 0; n < 32; n++) {
        float e = expf(drs[n] * fd);
        float ph = dis[n] * fd;
        acc += c2r[n] * e * cosf(ph) - c2i[n] * e * sinf(ph);
    }
    if (t == 0) acc += Dskip[ch];
    Kl[t] = acc;
    __syncthreads();
    f16* T = (f16*)(ws + OFF_T) + (size_t)ch * 65536;
    for (int r = 0; r < 256; r++) {
        float v = (t <= r) ? Kl[r - t] : 0.0f;
        T[r * 256 + t] = (f16)v;
    }
    f16* V = (f16*)(ws + OFF_V) + (size_t)ch * 16384;
    float fe = (float)(255 - t);
    for (int row = 0; row < 64; row++) {
        int n = row & 31;
        float e = expf(drs[n] * fe);
        float ph = dis[n] * fe;
        float val = (row < 32) ? e * cosf(ph) : e * sinf(ph);
        V[row * 256 + t] = (f16)val;
    }
    f16* U = (f16*)(ws + OFF_U) + (size_t)ch * 16384;
    int col = t & 63, lp = t >> 6;
    int n = col >> 1, ri = col & 1;
    for (int li = 0; li < 64; li++) {
        int l = li * 4 + lp;
        float fl1 = (float)(l + 1);
        float e = expf(drs[n] * fl1);
        float ph = dis[n] * fl1;
        float wre = e * cosf(ph), wim = e * sinf(ph);
        float re = c2r[n] * wre - c2i[n] * wim;
        float im = c2r[n] * wim + c2i[n] * wre;
        U[l * 64 + col] = (f16)(ri ? -im : re);
    }
}

// ---------------------------------------------------------------------------
// CM1: h = prelu(linear_w @ x + b), fp32 in -> f16 out. (r1 LDS-W form)
// ---------------------------------------------------------------------------
__global__ __launch_bounds__(256) void k_cm1(const float* __restrict__ x,
                                             const float* __restrict__ W,
                                             const float* __restrict__ bias,
                                             f16* __restrict__ dst,
                                             const float* __restrict__ aptr) {
    __shared__ __align__(16) float Wl[4096];
    __shared__ float bl[64];
    int t = threadIdx.x, bi = blockIdx.x;
    int b = bi >> 6;
    int l = ((bi & 63) << 8) + t;
    for (int i = 0; i < 16; i++) Wl[t + i * 256] = W[t + i * 256];
    if (t < 64) bl[t] = bias[t];
    __syncthreads();
    float a1 = *aptr;
    const float* sp = x + (size_t)b * HH * LL + l;
    float xv[64];
#pragma unroll
    for (int ch = 0; ch < 64; ch++) xv[ch] = sp[(size_t)ch * LL];
    f16* dp = dst + (size_t)b * HH * LL + l;
    for (int g = 0; g < 64; g++) {
        float acc = bl[g];
#pragma unroll
        for (int hh = 0; hh < 16; hh++) {
            float4 wv = *(const float4*)&Wl[g * 64 + hh * 4];
            acc = fmaf(wv.x, xv[hh * 4 + 0], acc);
            acc = fmaf(wv.y, xv[hh * 4 + 1], acc);
            acc = fmaf(wv.z, xv[hh * 4 + 2], acc);
            acc = fmaf(wv.w, xv[hh * 4 + 3], acc);
        }
        acc = (acc >= 0.0f) ? acc : a1 * acc;
        dp[(size_t)g * LL] = (f16)acc;
    }
}

// ---------------------------------------------------------------------------
// CM2: y2 = out_w @ y1 + out_b, f16 in -> fp32 out.
// ---------------------------------------------------------------------------
__global__ __launch_bounds__(256) void k_cm2(const f16* __restrict__ y1,
                                             const float* __restrict__ W,
                                             const float* __restrict__ bias,
                                             float* __restrict__ dst) {
    __shared__ __align__(16) float Wl[4096];
    __shared__ float bl[64];
    int t = threadIdx.x, bi = blockIdx.x;
    int b = bi >> 6;
    int l = ((bi & 63) << 8) + t;
    for (int i = 0; i < 16; i++) Wl[t + i * 256] = W[t + i * 256];
    if (t < 64) bl[t] = bias[t];
    __syncthreads();
    const f16* sp = y1 + (size_t)b * HH * LL + l;
    float xv[64];
#pragma unroll
    for (int ch = 0; ch < 64; ch++) xv[ch] = (float)sp[(size_t)ch * LL];
    float* dp = dst + (size_t)b * HH * LL + l;
    for (int g = 0; g < 64; g++) {
        float acc = bl[g];
#pragma unroll
        for (int hh = 0; hh < 16; hh++) {
            float4 wv = *(const float4*)&Wl[g * 64 + hh * 4];
            acc = fmaf(wv.x, xv[hh * 4 + 0], acc);
            acc = fmaf(wv.y, xv[hh * 4 + 1], acc);
            acc = fmaf(wv.z, xv[hh * 4 + 2], acc);
            acc = fmaf(wv.w, xv[hh * 4 + 3], acc);
        }
        dp[(size_t)g * LL] = acc;
    }
}

// ---------------------------------------------------------------------------
// GEMM A: P(64x1024) = V(64x256) @ H(256x1024) per channel, fp32 out.
// grid 256: ch = bid&63, ntile = bid>>6 (N-tile of 256 cols).
// ---------------------------------------------------------------------------
__global__ __launch_bounds__(256) void gemmA(float* __restrict__ ws) {
    __shared__ __align__(16) char smem[25600];
    f16* Vs = (f16*)smem;                 // [64][stride 40]
    f16* Hs = (f16*)(smem + 5120);        // [256][stride 40]
    int t = threadIdx.x;
    int bid = blockIdx.x;
    int ch = bid & 63, ntile = bid >> 6;
    const f16* Vm = (const f16*)(ws + OFF_V) + (size_t)ch * 16384;
    const f16* H  = (const f16*)(ws + OFF_H);
    int w = t >> 6, lane = t & 63;
    int qd = lane >> 4, ln = lane & 15;
    f32x4 acc[4][4];
#pragma unroll
    for (int a = 0; a < 4; a++)
#pragma unroll
        for (int nb = 0; nb < 4; nb++) acc[a][nb] = (f32x4)0.0f;
    int colg = ntile * 256 + t;
    const f16* hcol = H + ((size_t)(colg >> 6) * 64 + ch) * 16384 + (size_t)(colg & 63) * 256;
    int vrow = t >> 2, vkg = t & 3;
    for (int k0 = 0; k0 < 256; k0 += 32) {
        __syncthreads();
        *(float4*)&Vs[vrow * 40 + vkg * 8] = *(const float4*)(Vm + vrow * 256 + k0 + vkg * 8);
#pragma unroll
        for (int kg = 0; kg < 4; kg++)
            *(float4*)&Hs[t * 40 + kg * 8] = *(const float4*)(hcol + k0 + kg * 8);
        __syncthreads();
        f16x8 af[4], bf[4];
#pragma unroll
        for (int a = 0; a < 4; a++) af[a] = *(f16x8*)&Vs[(a * 16 + ln) * 40 + qd * 8];
#pragma unroll
        for (int nb = 0; nb < 4; nb++) bf[nb] = *(f16x8*)&Hs[(w * 64 + nb * 16 + ln) * 40 + qd * 8];
#pragma unroll
        for (int a = 0; a < 4; a++)
#pragma unroll
            for (int nb = 0; nb < 4; nb++)
                acc[a][nb] = __builtin_amdgcn_mfma_f32_16x16x32_f16(af[a], bf[nb], acc[a][nb], 0, 0, 0);
    }
    float* P = ws + OFF_P;
#pragma unroll
    for (int a = 0; a < 4; a++)
#pragma unroll
        for (int nb = 0; nb < 4; nb++)
#pragma unroll
            for (int r = 0; r < 4; r++) {
                int row = a * 16 + qd * 4 + r;
                int col = ntile * 256 + w * 64 + nb * 16 + ln;
                P[((size_t)ch * 64 + row) * 1024 + col] = acc[a][nb][r];
            }
}

// ---------------------------------------------------------------------------
// K3: sequential carry scan over chunks; writes S_in per chunk as f16 (S_t).
// ---------------------------------------------------------------------------
__global__ __launch_bounds__(256) void k3_scan(float* __restrict__ ws) {
    int tid = blockIdx.x * 256 + threadIdx.x;  // 0..32767
    int ch = tid >> 9, b = (tid >> 5) & 15, n = tid & 31;
    const float* P = ws + OFF_P;
    f16* S = (f16*)(ws + OFF_S);
    float2 wl = ((const float2*)(ws + OFF_WL))[ch * 32 + n];
    float sr = 0.0f, si = 0.0f;
    const float* pre = P + ((size_t)ch * 64 + n) * 1024 + b * 64;
    const float* pim = P + ((size_t)ch * 64 + 32 + n) * 1024 + b * 64;
    f16* srow = S + ((size_t)ch * 1024 + b * 64) * 64 + 2 * n;
    for (int c = 0; c < 64; c++) {
        srow[c * 64]     = (f16)sr;
        srow[c * 64 + 1] = (f16)si;
        float pr = pre[c], pi = pim[c];
        float nr = fmaf(wl.x, sr, fmaf(-wl.y, si, pr));
        float ni = fmaf(wl.y, sr, fmaf(wl.x, si, pi));
        sr = nr; si = ni;
    }
}

// ---------------------------------------------------------------------------
// GEMM MAIN: per channel: Y1(256x1024) = T'(256x256)@H + U(256x64)@S.
// grid 1024: ch = bid&63 (XCD-colocated), ntile = bid>>6 (64 cols each).
// Triangular k-step skipping on the T phase. y1 f16 written IN PLACE over H
// (this block's own columns only — no cross-block hazard).
// ---------------------------------------------------------------------------
__global__ __launch_bounds__(256) void gemmMain(float* __restrict__ ws) {
    __shared__ __align__(16) char smem[25600];
    f16* Ts = (f16*)smem;                  // [256][stride 40] (also Us)
    f16* Hs = (f16*)(smem + 20480);        // [64][stride 40]  (also Ss)
    f16* Ys = (f16*)smem;                  // [64][stride 136]
    int t = threadIdx.x;
    int bid = blockIdx.x;
    int ch = bid & 63, ntile = bid >> 6;
    const f16* Tm = (const f16*)(ws + OFF_T) + (size_t)ch * 65536;
    const f16* Um = (const f16*)(ws + OFF_U) + (size_t)ch * 16384;
    const f16* H  = (const f16*)(ws + OFF_H);
    const f16* St = (const f16*)(ws + OFF_S);
    f16* y1 = (f16*)(ws + OFF_H);          // in-place over H
    int w = t >> 6, lane = t & 63;
    int qd = lane >> 4, ln = lane & 15;
    f32x4 acc[4][4];
#pragma unroll
    for (int a = 0; a < 4; a++)
#pragma unroll
        for (int nb = 0; nb < 4; nb++) acc[a][nb] = (f32x4)0.0f;
    int scol = t >> 2, skg = t & 3;        // staging role for Hs/Ss
    int colg = ntile * 64 + scol;
    const f16* hcol = H + ((size_t)(colg >> 6) * 64 + ch) * 16384 + (size_t)(colg & 63) * 256;
    const f16* sscol = St + ((size_t)ch * 1024 + colg) * 64;
    // ---- T @ H ----
    for (int k0 = 0; k0 < 256; k0 += 32) {
        __syncthreads();
#pragma unroll
        for (int kg = 0; kg < 4; kg++)
            *(float4*)&Ts[t * 40 + kg * 8] = *(const float4*)(Tm + t * 256 + k0 + kg * 8);
        *(float4*)&Hs[scol * 40 + skg * 8] = *(const float4*)(hcol + k0 + skg * 8);
        __syncthreads();
        if (k0 <= w * 64 + 63) {
            f16x8 bf[4];
#pragma unroll
            for (int nb = 0; nb < 4; nb++) bf[nb] = *(f16x8*)&Hs[(nb * 16 + ln) * 40 + qd * 8];
#pragma unroll
            for (int a = 0; a < 4; a++) {
                if (k0 <= w * 64 + a * 16 + 15) {
                    f16x8 af = *(f16x8*)&Ts[(w * 64 + a * 16 + ln) * 40 + qd * 8];
#pragma unroll
                    for (int nb = 0; nb < 4; nb++)
                        acc[a][nb] = __builtin_amdgcn_mfma_f32_16x16x32_f16(af, bf[nb], acc[a][nb], 0, 0, 0);
                }
            }
        }
    }
    // ---- U @ S ----
    for (int k0 = 0; k0 < 64; k0 += 32) {
        __syncthreads();
#pragma unroll
        for (int kg = 0; kg < 4; kg++)
            *(float4*)&Ts[t * 40 + kg * 8] = *(const float4*)(Um + t * 64 + k0 + kg * 8);
        *(float4*)&Hs[scol * 40 + skg * 8] = *(const float4*)(sscol + k0 + skg * 8);
        __syncthreads();
        f16x8 bf[4];
#pragma unroll
        for (int nb = 0; nb < 4; nb++) bf[nb] = *(f16x8*)&Hs[(nb * 16 + ln) * 40 + qd * 8];
#pragma unroll
        for (int a = 0; a < 4; a++) {
            f16x8 af = *(f16x8*)&Ts[(w * 64 + a * 16 + ln) * 40 + qd * 8];
#pragma unroll
            for (int nb = 0; nb < 4; nb++)
                acc[a][nb] = __builtin_amdgcn_mfma_f32_16x16x32_f16(af, bf[nb], acc[a][nb], 0, 0, 0);
        }
    }
    // ---- epilogue: transpose through LDS, write y1 f16 [b][ch][l] in place ----
    int ocol = t >> 2, ojg = t & 3;
    int ocolg = ntile * 64 + ocol;
    f16* ybase = y1 + ((size_t)(ocolg >> 6) * 64 + ch) * 16384 + (size_t)(ocolg & 63) * 256;
    for (int hf = 0; hf < 2; hf++) {
        __syncthreads();
        if ((w >> 1) == hf) {
            int jl0 = (w & 1) * 64;
#pragma unroll
            for (int a = 0; a < 4; a++)
#pragma unroll
                for (int nb = 0; nb < 4; nb++)
#pragma unroll
                    for (int r = 0; r < 4; r++)
                        Ys[(nb * 16 + ln) * 136 + jl0 + a * 16 + qd * 4 + r] = (f16)acc[a][nb][r];
        }
        __syncthreads();
#pragma unroll
        for (int i = 0; i < 4; i++)
            *(float4*)(ybase + hf * 128 + ojg * 32 + i * 8) =
                *(const float4*)&Ys[ocol * 136 + ojg * 32 + i * 8];
    }
}

// ---------------------------------------------------------------------------
// K5b: BN partial sums per channel (one block per (b,ch) row).
// ---------------------------------------------------------------------------
__global__ __launch_bounds__(256) void k5b_bnsum(const float* __restrict__ y2,
                                                 float* __restrict__ ws) {
    int bi = blockIdx.x;
    int t = threadIdx.x;
    const float4* r4 = (const float4*)(y2 + (size_t)bi * LL);
    float s = 0.0f, ss = 0.0f;
    for (int i = 0; i < 16; i++) {
        float4 v = r4[t + i * 256];
        s += v.x + v.y + v.z + v.w;
        ss += v.x * v.x + v.y * v.y + v.z * v.z + v.w * v.w;
    }
    for (int off = 32; off; off >>= 1) {
        s += __shfl_xor(s, off);
        ss += __shfl_xor(ss, off);
    }
    __shared__ float wsum[4], wsq[4];
    int wv = t >> 6;
    if ((t & 63) == 0) { wsum[wv] = s; wsq[wv] = ss; }
    __syncthreads();
    if (t == 0) {
        float S = wsum[0] + wsum[1] + wsum[2] + wsum[3];
        float SS = wsq[0] + wsq[1] + wsq[2] + wsq[3];
        int ch = bi & 63;
        atomicAdd(ws + OFF_BN + ch, S);
        atomicAdd(ws + OFF_BN + 64 + ch, SS);
    }
}

__global__ void k5c_bnfin(float* __restrict__ ws) {
    int t = threadIdx.x;
    float cnt = (float)BL;
    float mean = ws[OFF_BN + t] / cnt;
    float var = ws[OFF_BN + 64 + t] / cnt - mean * mean;
    ws[OFF_BNF + t] = mean;
    ws[OFF_BNF + 64 + t] = 1.0f / sqrtf(var + 1e-5f);
}

// ---------------------------------------------------------------------------
// K6: BN apply + FiLM + PReLU + depthwise residual, in-place over d_out.
// ---------------------------------------------------------------------------
__global__ __launch_bounds__(256) void k6_final(const float* __restrict__ x,
                                                const float* __restrict__ ws,
                                                const float* __restrict__ a2p,
                                                const float* __restrict__ res_w,
                                                float* __restrict__ out) {
    int bi = blockIdx.x;
    int t = threadIdx.x;
    int row = bi >> 4;
    int b = row >> 6, ch = row & 63;
    float gamma = ws[OFF_GB + b * 128 + ch];
    float beta  = ws[OFF_GB + b * 128 + 64 + ch];
    float mean = ws[OFF_BNF + ch];
    float inv  = ws[OFF_BNF + 64 + ch];
    float scale = gamma * inv;
    float shift = beta - scale * mean;
    float rw = res_w[ch];
    float a2 = *a2p;
    size_t i4 = (size_t)row * (LL / 4) + (size_t)(bi & 15) * 256 + t;
    float4 y = ((const float4*)out)[i4];
    float4 xv = ((const float4*)x)[i4];
    float v;
    v = fmaf(scale, y.x, shift); v = (v >= 0.0f) ? v : a2 * v; y.x = fmaf(rw, xv.x, v);
    v = fmaf(scale, y.y, shift); v = (v >= 0.0f) ? v : a2 * v; y.y = fmaf(rw, xv.y, v);
    v = fmaf(scale, y.z, shift); v = (v >= 0.0f) ? v : a2 * v; y.z = fmaf(rw, xv.z, v);
    v = fmaf(scale, y.w, shift); v = (v >= 0.0f) ? v : a2 * v; y.w = fmaf(rw, xv.w, v);
    ((float4*)out)[i4] = y;
}

// ---------------------------------------------------------------------------
extern "C" void kernel_launch(void* const* d_in, const int* in_sizes, int n_in,
                              void* d_out, int out_size, void* d_ws, size_t ws_size,
                              hipStream_t stream) {
    const float* x        = (const float*)d_in[0];
    const float* cond     = (const float*)d_in[1];
    const float* linear_w = (const float*)d_in[2];
    const float* linear_b = (const float*)d_in[3];
    const float* prelu1_a = (const float*)d_in[4];
    const float* log_dt   = (const float*)d_in[5];
    const float* log_A    = (const float*)d_in[6];
    const float* A_imag   = (const float*)d_in[7];
    const float* C_re     = (const float*)d_in[8];
    const float* C_im     = (const float*)d_in[9];
    const float* Dskip    = (const float*)d_in[10];
    const float* out_w    = (const float*)d_in[11];
    const float* out_b    = (const float*)d_in[12];
    const float* film_w   = (const float*)d_in[13];
    const float* film_b   = (const float*)d_in[14];
    const float* prelu2_a = (const float*)d_in[15];
    const float* res_w    = (const float*)d_in[16];
    float* ws  = (float*)d_ws;
    float* out = (float*)d_out;
    f16* hbuf = (f16*)(ws + OFF_H);
    f16* y1   = (f16*)(ws + OFF_H);   // y1 aliases h (overwritten in place)

    hipLaunchKernelGGL(k0_setup, dim3(3), dim3(256), 0, stream,
                       log_dt, log_A, A_imag, C_re, C_im, cond, film_w, film_b, ws);
    hipLaunchKernelGGL(kbuild, dim3(64), dim3(256), 0, stream,
                       log_dt, log_A, A_imag, Dskip, ws);
    hipLaunchKernelGGL(k_cm1, dim3(1024), dim3(256), 0, stream,
                       x, linear_w, linear_b, hbuf, prelu1_a);
    hipLaunchKernelGGL(gemmA, dim3(256), dim3(256), 0, stream, ws);
    hipLaunchKernelGGL(k3_scan, dim3(128), dim3(256), 0, stream, ws);
    hipLaunchKernelGGL(gemmMain, dim3(1024), dim3(256), 0, stream, ws);
    hipLaunchKernelGGL(k_cm2, dim3(1024), dim3(256), 0, stream,
                       y1, out_w, out_b, out);
    hipLaunchKernelGGL(k5b_bnsum, dim3(1024), dim3(256), 0, stream, out, ws);
    hipLaunchKernelGGL(k5c_bnfin, dim3(1), dim3(64), 0, stream, ws);
    hipLaunchKernelGGL(k6_final, dim3(16384), dim3(256), 0, stream,
                       x, ws, prelu2_a, res_w, out);
}